// Round 3
// baseline (218.640 us; speedup 1.0000x reference)
//
#include <hip/hip_runtime.h>
#include <math.h>

#define KK      7
#define C1      21
#define NPLANES (KK * KK * C1)   // 1029
#define H       100
#define W       100
#define HH      50               // half extent for split scans
#define TS      101              // padded LDS row stride: bank stride 5 (coprime 32)
#define NCHUNK  ((H * W) / 4)    // 2500 float4 chunks per plane
#define PREFK   10               // ceil(2500 / 256)

// ---------------------------------------------------------------------------
// Two-kernel structure (proven).  Round-3 changes target plane_partial's
// per-block serial critical path (the controllable ~20us of the ~215us total):
//  - row scan: 2 threads/row (50 steps instead of 100); left-half totals in
//    rfix[], folded into the col scan at zero cost (broadcast read per step).
//  - col scan: top/bottom halves scanned independently (50 steps); straddle
//    correction g*(T(x1)-T(x0-1)) with T = tile[49][*] folded into the ROI
//    lookup (only rects crossing row 50 pay 2 extra LDS reads).
//  - ROI loop: next int4 roi prefetched one iteration ahead (hides ~250cy L2
//    latency; loop isn't unrollable since nrois is runtime).
// Round-1 lesson kept: no scatter atomics to out[]; coalesced partial[] only.
// ---------------------------------------------------------------------------
__global__ __launch_bounds__(256) void plane_partial(
    const float* __restrict__ src,   // full cls_conv_out
    size_t batch_off,                // offset of last batch element (elements)
    const int*  __restrict__ rois,   // [nrois][4] = ymin,xmin,ymax,xmax
    int nrois,
    float* __restrict__ partial)     // [NPLANES][nrois]
{
    const int t  = threadIdx.x;
    const int p0 = blockIdx.x * 2;
    const int p1 = p0 + 1;
    const bool has_p1 = (p1 < NPLANES);

    __shared__ float tile[H * TS];   // 40400 B
    __shared__ float rfix[H];        // left-half row sums (400 B)

    // ---- stage plane 0 (float4 global -> scalar padded LDS) ----
    {
        const float4* p4 = (const float4*)(src + batch_off + (size_t)p0 * (H * W));
        #pragma unroll
        for (int k = 0; k < PREFK; ++k) {
            int i = t + 256 * k;
            if (i < NCHUNK) {
                float4 v = p4[i];
                int g = i * 4;
                int y = g / W, x = g - y * W;        // rows don't split (100%4==0)
                float* d = &tile[y * TS + x];
                d[0] = v.x; d[1] = v.y; d[2] = v.z; d[3] = v.w;
            }
        }
    }
    __syncthreads();

    // ---- issue prefetch of plane 1 into registers (loads stay in flight) ----
    float4 pref[PREFK];
    if (has_p1) {
        const float4* p4 = (const float4*)(src + batch_off + (size_t)p1 * (H * W));
        #pragma unroll
        for (int k = 0; k < PREFK; ++k) {
            int i = t + 256 * k;
            if (i < NCHUNK) pref[k] = p4[i];
        }
    }

    const int4* rois4 = (const int4*)rois;

    for (int pass = 0; pass < 2; ++pass) {
        const int p = p0 + pass;
        if (p >= NPLANES) break;
        const int jl = p / C1;
        const int l  = jl % KK;
        const int j  = jl / KK;

        if (pass == 1) {
            // overwrite tile with the prefetched plane
            __syncthreads();          // all pass-0 tile reads done
            #pragma unroll
            for (int k = 0; k < PREFK; ++k) {
                int i = t + 256 * k;
                if (i < NCHUNK) {
                    float4 v = pref[k];
                    int g = i * 4;
                    int y = g / W, x = g - y * W;
                    float* d = &tile[y * TS + x];
                    d[0] = v.x; d[1] = v.y; d[2] = v.z; d[3] = v.w;
                }
            }
            __syncthreads();
        }

        // ---- row-prefix, split: thread (r, seg) scans 50 elems of row r.
        // bank(step x): addr = 101r + 50seg + x -> (5r + 18seg + x) & 31;
        // across a wave: {5r} distinct (coprime), seg-shifted set overlaps
        // 2-way max -> conflict-free per m136.
        if (t < 2 * H) {
            const int r   = t >> 1;
            const int seg = t & 1;
            float* row = &tile[r * TS + seg * HH];
            float s = 0.f;
            #pragma unroll 10
            for (int x = 0; x < HH; ++x) { s += row[x]; row[x] = s; }
            if (seg == 0) rfix[r] = s;   // left-half total
        }
        __syncthreads();

        // ---- col-prefix, split: thread (c, h) scans 50 rows of column c in
        // half h, adding rfix[y] for right-half columns (broadcast read).
        // After this, tile[y][c] = integral WITHIN its half; top-half column
        // totals are tile[49][c].
        if (t < 2 * W) {
            const int c  = t >> 1;
            const int h  = t & 1;
            const int yb = h * HH;
            const bool addfix = (c >= HH);
            float s = 0.f;
            #pragma unroll 10
            for (int i = 0; i < HH; ++i) {
                const int y = yb + i;
                float v = tile[y * TS + c];
                if (addfix) v += rfix[y];
                s += v;
                tile[y * TS + c] = s;
            }
        }
        __syncthreads();

        // ---- ROI lookups on the half-integral.
        // I(y,x) = tile[y][x] + (y>=50 ? T(x) : 0), T(x) = tile[49][x].
        // S = I(y1,x1) - I(y0-1,x1) - I(y1,x0-1) + I(y0-1,x0-1)
        //   = base(4 half-terms) + g*(T(x1) - T(x0-1)),
        //   g = (y1>=50) - (y0-1>=50)  in {0,1}  (y0-1<0 counts as <50 -> 0).
        float* prow = partial + (size_t)p * nrois;
        if (t < nrois) {
            int4 r = rois4[t];                       // first roi, prefetched
            for (int n = t; n < nrois; n += 256) {
                const int nn = n + 256;
                const int4 rnext = (nn < nrois) ? rois4[nn] : r;  // hide L2 latency

                const int ys  = (r.z - r.x) / KK;
                const int xs  = (r.w - r.y) / KK;
                const int y0  = r.x + j * ys;
                const int x0  = r.y + l * xs;
                const int y1  = y0 + ys - 1;          // <= 94 < 100
                const int x1  = x0 + xs - 1;

                float S = tile[y1 * TS + x1];
                if (x0 > 0)           S -= tile[y1 * TS + (x0 - 1)];
                if (y0 > 0)           S -= tile[(y0 - 1) * TS + x1];
                if (y0 > 0 && x0 > 0) S += tile[(y0 - 1) * TS + (x0 - 1)];

                const int g = (y1 >= HH) - (y0 - 1 >= HH);
                if (g) {
                    float T = tile[(HH - 1) * TS + x1];
                    if (x0 > 0) T -= tile[(HH - 1) * TS + (x0 - 1)];
                    S += T;
                }

                prow[n] = S;                          // coalesced 4B store
                r = rnext;
            }
        }
    }
}

// ---------------------------------------------------------------------------
// Stage 2 (fused reduce + softmax): block handles RB=16 ROIs.
// Thread (dn = t%16, cg = t/16) sums channels c = cg, cg+16 over 49 planes
// with 64B-coalesced loads (16 consecutive n per channel-row).  LDS ch[16][21],
// then lanes 0..15 do the per-ROI scale + softmax + store.
// ---------------------------------------------------------------------------
#define RB 16

__global__ __launch_bounds__(256) void reduce_softmax(
    const float* __restrict__ partial,   // [NPLANES][nrois]
    const int*   __restrict__ rois,
    int nrois,
    float*       __restrict__ out)
{
    const int dn = threadIdx.x & (RB - 1);
    const int cg = threadIdx.x / RB;     // 0..15
    const int n  = blockIdx.x * RB + dn;

    __shared__ float ch[RB][C1];

    if (n < nrois) {
        for (int c = cg; c < C1; c += 16) {
            float s = 0.f;
            const float* pc = partial + (size_t)c * nrois + n;
            #pragma unroll
            for (int jl = 0; jl < KK * KK; ++jl) {
                s += pc[(size_t)jl * C1 * nrois];
            }
            ch[dn][c] = s;
        }
    }
    __syncthreads();

    if (threadIdx.x < RB) {
        const int n2 = blockIdx.x * RB + threadIdx.x;
        if (n2 < nrois) {
            const int4 r  = ((const int4*)rois)[n2];
            const int ys  = (r.z - r.x) / KK;
            const int xs  = (r.w - r.y) / KK;
            const float inv = 1.0f / (49.0f * (float)(ys * xs));

            float v[C1];
            float m = -INFINITY;
            #pragma unroll
            for (int c = 0; c < C1; ++c) {
                v[c] = ch[threadIdx.x][c] * inv;
                m = fmaxf(m, v[c]);
            }
            float s = 0.f;
            #pragma unroll
            for (int c = 0; c < C1; ++c) { v[c] = __expf(v[c] - m); s += v[c]; }
            const float rs = 1.0f / s;
            #pragma unroll
            for (int c = 0; c < C1; ++c) out[(size_t)n2 * C1 + c] = v[c] * rs;
        }
    }
}

// ---------------------------------------------------------------------------
// Fallback (ws too small): direct rectangle summation from global.
// ---------------------------------------------------------------------------
__global__ __launch_bounds__(256) void roi_pool_direct(
    const float* __restrict__ src,
    size_t batch_off,
    const int*   __restrict__ rois,
    float*       __restrict__ out)
{
    const int n = blockIdx.x;
    const int t = threadIdx.x;

    __shared__ float chsum[C1];
    if (t < C1) chsum[t] = 0.f;
    __syncthreads();

    const int ymin = rois[4 * n + 0];
    const int xmin = rois[4 * n + 1];
    const int ymax = rois[4 * n + 2];
    const int xmax = rois[4 * n + 3];
    const int ys = (ymax - ymin) / KK;
    const int xs = (xmax - xmin) / KK;

    const float* base = src + batch_off;

    for (int idx = t; idx < NPLANES; idx += blockDim.x) {
        const int c  = idx % C1;
        const int jl = idx / C1;
        const int l  = jl % KK;
        const int j  = jl / KK;
        const int y0 = ymin + j * ys;
        const int x0 = xmin + l * xs;
        const float* plane = base + (size_t)idx * (H * W);
        float s = 0.f;
        for (int y = y0; y < y0 + ys; ++y) {
            const float* row = plane + (size_t)y * W + x0;
            for (int x = 0; x < xs; ++x) s += row[x];
        }
        atomicAdd(&chsum[c], s);
    }
    __syncthreads();

    if (t == 0) {
        const float inv = 1.0f / (49.0f * (float)(ys * xs));
        float m = -INFINITY;
        float v[C1];
        for (int c = 0; c < C1; ++c) { v[c] = chsum[c] * inv; m = fmaxf(m, v[c]); }
        float s = 0.f;
        for (int c = 0; c < C1; ++c) { v[c] = expf(v[c] - m); s += v[c]; }
        const float rs = 1.0f / s;
        for (int c = 0; c < C1; ++c) out[(size_t)n * C1 + c] = v[c] * rs;
    }
}

extern "C" void kernel_launch(void* const* d_in, const int* in_sizes, int n_in,
                              void* d_out, int out_size, void* d_ws, size_t ws_size,
                              hipStream_t stream)
{
    const float* cls  = (const float*)d_in[0];
    const int*   rois = (const int*)d_in[1];
    float*       out  = (float*)d_out;

    const int nrois = in_sizes[1] / 4;                         // 2000
    const size_t plane_elems = (size_t)NPLANES * H * W;        // 10.29 M
    const int B = (int)((size_t)in_sizes[0] / plane_elems);    // 4
    const size_t batch_off = (size_t)(B - 1) * plane_elems;

    const size_t need = (size_t)NPLANES * nrois * sizeof(float);  // ~8.2 MB
    if (ws_size >= need) {
        float* partial = (float*)d_ws;
        const int nblocks = (NPLANES + 1) / 2;                 // 515
        plane_partial<<<nblocks, 256, 0, stream>>>(cls, batch_off, rois, nrois, partial);
        reduce_softmax<<<(nrois + RB - 1) / RB, 256, 0, stream>>>(partial, rois, nrois, out);
    } else {
        roi_pool_direct<<<nrois, 256, 0, stream>>>(cls, batch_off, rois, out);
    }
}